// Round 14
// baseline (240.866 us; speedup 1.0000x reference)
//
#include <hip/hip_runtime.h>
#include <stdint.h>

#define NB 32768
#define NPASS 4
#define FULL27 0x07FFFFFFu
#define NBF (NB * 729)     // total floats = 23,887,872
#define PPW 32             // puzzles per wave-block: 16 triples x 2 (ILP=2)
#define NBLK (NB / PPW)    // 1024 blocks, no tail

// Per-band bitboard: digit d, band b (rows 3b..3b+2), bit (r*9+c).
// BOX k mask within band: 0x1C0E07 << 3k ; COL c: 0x40201 << c ; ROW r: 0x1FF << 9r
// Flat float layout: puzzle p, digit d, band b, cell j  ==  p*729 + d*81 + b*27 + j.

__device__ __forceinline__ uint32_t colfold(uint32_t w) {
    return (w | (w >> 9) | (w >> 18)) & 0x1FFu;
}
__device__ __forceinline__ uint32_t colmaj2(uint32_t w) {   // columns with >=2 bits in band
    return ((w & (w >> 9)) | ((w | (w >> 9)) & (w >> 18))) & 0x1FFu;
}

// ---------------- FULLY FUSED, ILP=2: pack + solve + expand ----------------
// r13 post-mortem: solve is dep-chain/DS-latency bound per wave (per-wave issue
// ~26% with idle slots). Fix: each lane-triple handles TWO puzzles (u=0,1) --
// two independent dep chains co-schedule, halving effective per-puzzle latency.
// Block = 64 threads = 1 wave = 32 puzzles; grid = 1024 (1 wave/SIMD, no tail).
// Solve math is the validated r6/r8 code mechanically duplicated over u.
__global__ __launch_bounds__(64)
void sudoku_kernel(const uint32_t* __restrict__ in, float* __restrict__ out,
                   float* __restrict__ solved) {
    __shared__ uint32_t pool[744];          // 23328 bits = 729 dw (+junk/pad to 744)
    const int lane = threadIdx.x;
    const int trip = lane / 3;              // 0..21 (16..21 idle in solve)
    const int band = lane - trip * 3;
    const int bo1 = band == 2 ? 0 : band + 1;
    const int bo2 = band == 0 ? 2 : band - 1;
    int sl1 = trip * 3 + bo1; if (sl1 > 63) sl1 = 63;   // partner lanes
    int sl2 = trip * 3 + bo2; if (sl2 > 63) sl2 = 63;
    const int p0 = blockIdx.x * PPW;        // first puzzle of block
    const bool valid = (trip < 16);         // grid exact: no p-bound needed

    // ---------------- PACK: coalesced loads -> ballot -> wave pool ----------------
    // Pool bit j == input float p0*729 + j (j in [0, 23328)). 368 rounds (last 3.5 junk).
    {
        const int base = p0 * 729;                      // < 24M, fits int
        #pragma unroll 1
        for (int c = 0; c < 23; ++c) {                  // 23 chunks x 16 rounds
            uint32_t v[16];
            #pragma unroll
            for (int j = 0; j < 16; ++j) {
                int gi = base + (c * 16 + j) * 64 + lane;
                if (gi >= NBF) gi = NBF - 1;            // clamp (junk bits unused)
                v[j] = in[gi];
            }
            #pragma unroll
            for (int j = 0; j < 16; ++j) {
                unsigned long long m = __ballot(v[j] != 0u);
                if (lane == 0) {
                    int r = c * 16 + j;
                    pool[2 * r]     = (uint32_t)m;
                    pool[2 * r + 1] = (uint32_t)(m >> 32);
                }
            }
        }
    }
    __syncthreads();

    // ---------------- EXTRACT: 9 band-words x 2 puzzles ----------------
    uint32_t bd[2][9];
    {
        const int tx = trip > 15 ? 15 : trip;           // keep idle lanes in-bounds
        #pragma unroll
        for (int u = 0; u < 2; ++u) {
            const int bb0 = (u * 16 + tx) * 729 + band * 27;
            #pragma unroll
            for (int d = 0; d < 9; ++d) {
                int bb = bb0 + d * 81;
                int di = bb >> 5, sh = bb & 31;
                uint64_t both = (uint64_t)pool[di] | ((uint64_t)pool[di + 1] << 32);
                bd[u][d] = (uint32_t)(both >> sh) & FULL27;
            }
        }
    }
    __syncthreads();    // extraction done before the pool is zeroed for expand

    // ---------------- SOLVE (validated r6/r8 logic, duplicated over u) ----------------
    #pragma unroll 1
    for (int pass = 0; pass < NPASS; ++pass) {
        // ---------- filter 'box' (band-local) ----------
        #pragma unroll
        for (int u = 0; u < 2; ++u) {
            uint32_t on = 0, tw = 0, fo = 0;
            #pragma unroll
            for (int d = 0; d < 9; ++d) {
                uint32_t c = on & bd[u][d];
                on ^= bd[u][d]; fo |= tw & c; tw ^= c;
            }
            uint32_t ex1 = on & ~tw & ~fo;
            #pragma unroll
            for (int d = 0; d < 9; ++d) {
                uint32_t s = bd[u][d] & ex1;
                #pragma unroll
                for (int k = 0; k < 3; ++k) {
                    uint32_t bm = 0x1C0E07u << (3 * k);
                    uint32_t sm = s & bm;
                    uint32_t multi = sm & (sm - 1u);
                    uint32_t keep = (sm == 0u) ? 0xFFFFFFFFu : (~bm | (multi ? 0u : sm));
                    bd[u][d] &= keep;
                }
            }
        }

        // ---------- pointing 'h' (band-local) ----------
        #pragma unroll
        for (int u = 0; u < 2; ++u)
            #pragma unroll
            for (int d = 0; d < 9; ++d) {
                uint32_t w = bd[u][d];
                uint32_t t = (w | (w >> 1) | (w >> 2)) & 0x01249249u;
                uint32_t sum = (t & 0x1FFu) + ((t >> 9) & 0x1FFu) + ((t >> 18) & 0x1FFu);
                uint32_t single = sum & ~(sum >> 1) & 0x49u;
                uint32_t point = t & (single * 0x40201u);
                uint32_t clearm = 0;
                #pragma unroll
                for (int r = 0; r < 3; ++r) {
                    uint32_t pr = (point >> (9 * r)) & 0x1FFu;
                    uint32_t multi = pr & (pr - 1u);
                    uint32_t segkeep = multi ? 0u : pr * 7u;
                    uint32_t rc = pr ? ((0x1FFu & ~segkeep) << (9 * r)) : 0u;
                    clearm |= rc;
                }
                bd[u][d] = w & ~clearm;
            }

        // ---------- pointing 'v' (cross-band via shuffle) ----------
        #pragma unroll
        for (int u = 0; u < 2; ++u) {
            uint32_t pnt[9];
            #pragma unroll
            for (int d = 0; d < 9; ++d) {
                uint32_t w = bd[u][d];
                uint32_t q = colfold(w);
                uint32_t uu = (q & 0x49u) + ((q >> 1) & 0x49u) + ((q >> 2) & 0x49u);
                uint32_t single = uu & ~(uu >> 1) & 0x49u;
                pnt[d] = q & (single * 7u);
            }
            #pragma unroll
            for (int d = 0; d < 9; ++d) {
                uint32_t o = (uint32_t)__shfl((int)pnt[d], sl1, 64) |
                             (uint32_t)__shfl((int)pnt[d], sl2, 64);
                bd[u][d] &= ~(o * 0x40201u);
            }
        }

        // ---------- unique 'h' (band-local) ----------
        #pragma unroll
        for (int u = 0; u < 2; ++u) {
            uint32_t hid[9], has = 0;
            #pragma unroll
            for (int d = 0; d < 9; ++d) {
                uint32_t w = bd[u][d], h = 0;
                #pragma unroll
                for (int r = 0; r < 3; ++r) {
                    uint32_t x = w & (0x1FFu << (9 * r));
                    h |= (x & (x - 1u)) ? 0u : x;
                }
                hid[d] = h; has |= h;
            }
            #pragma unroll
            for (int d = 0; d < 9; ++d) bd[u][d] = (bd[u][d] & ~has) | hid[d];
        }

        // ---------- unique 'v' (cross-band via shuffle) ----------
        #pragma unroll
        for (int u = 0; u < 2; ++u) {
            uint32_t hid[9], has = 0;
            #pragma unroll
            for (int d = 0; d < 9; ++d) {
                uint32_t w = bd[u][d];
                uint32_t q0 = colfold(w), m0 = colmaj2(w);
                uint32_t ex = q0 | (m0 << 9);
                uint32_t ea = (uint32_t)__shfl((int)ex, sl1, 64);
                uint32_t eb = (uint32_t)__shfl((int)ex, sl2, 64);
                uint32_t qa = ea & 0x1FFu, ma = ea >> 9;
                uint32_t qb = eb & 0x1FFu, mb = eb >> 9;
                uint32_t ge2 = m0 | ma | mb | (q0 & qa) | (q0 & qb) | (qa & qb);
                uint32_t ex1c = (q0 | qa | qb) & ~ge2;   // column total count == 1
                hid[d] = w & ((ex1c & q0) * 0x40201u);
                has |= hid[d];
            }
            #pragma unroll
            for (int d = 0; d < 9; ++d) bd[u][d] = (bd[u][d] & ~has) | hid[d];
        }

        // ---------- unique 'box' (band-local) ----------
        #pragma unroll
        for (int u = 0; u < 2; ++u) {
            uint32_t hid[9], has = 0;
            #pragma unroll
            for (int d = 0; d < 9; ++d) {
                uint32_t w = bd[u][d], h = 0;
                #pragma unroll
                for (int k = 0; k < 3; ++k) {
                    uint32_t x = w & (0x1C0E07u << (3 * k));
                    h |= (x & (x - 1u)) ? 0u : x;
                }
                hid[d] = h; has |= h;
            }
            #pragma unroll
            for (int d = 0; d < 9; ++d) bd[u][d] = (bd[u][d] & ~has) | hid[d];
        }

        // ---------- doubles 'v' twice (cross-band via shuffle) ----------
        #pragma unroll 1
        for (int rep = 0; rep < 2; ++rep) {
            #pragma unroll
            for (int u = 0; u < 2; ++u) {
                uint32_t on = 0, tw = 0, fo = 0;
                #pragma unroll
                for (int d = 0; d < 9; ++d) {
                    uint32_t c = on & bd[u][d];
                    on ^= bd[u][d]; fo |= tw & c; tw ^= c;
                }
                uint32_t ex2 = tw & ~on & ~fo;
                uint32_t Q[9], K[9];
                #pragma unroll
                for (int d = 0; d < 9; ++d) { Q[d] = bd[u][d] & ex2; K[d] = 0u; }
                #pragma unroll
                for (int d1 = 0; d1 < 9; ++d1)
                    #pragma unroll
                    for (int d2 = d1 + 1; d2 < 9; ++d2) {
                        uint32_t P = Q[d1] & Q[d2];
                        uint32_t f0 = colfold(P), g0 = colmaj2(P);
                        uint32_t ex = f0 | (g0 << 9);
                        uint32_t ea = (uint32_t)__shfl((int)ex, sl1, 64);
                        uint32_t eb = (uint32_t)__shfl((int)ex, sl2, 64);
                        uint32_t fa = ea & 0x1FFu, ga = ea >> 9;
                        uint32_t fb = eb & 0x1FFu, gb = eb >> 9;
                        // columns with >=2 exact-pair cells across the full column
                        uint32_t dup = g0 | ga | gb | (f0 & fa) | (f0 & fb) | (fa & fb);
                        uint32_t sK = P & (dup * 0x40201u);
                        K[d1] |= sK; K[d2] |= sK;
                    }
                #pragma unroll
                for (int d = 0; d < 9; ++d) {
                    uint32_t kc = colfold(K[d]);
                    uint32_t cols = kc | (uint32_t)__shfl((int)kc, sl1, 64)
                                       | (uint32_t)__shfl((int)kc, sl2, 64);
                    uint32_t em = cols * 0x40201u;
                    bd[u][d] = (bd[u][d] & ~em) | K[d];
                }
            }
        }

        // ---------- doubles 'box' (band-local) ----------
        #pragma unroll
        for (int u = 0; u < 2; ++u) {
            uint32_t on = 0, tw = 0, fo = 0;
            #pragma unroll
            for (int d = 0; d < 9; ++d) {
                uint32_t c = on & bd[u][d];
                on ^= bd[u][d]; fo |= tw & c; tw ^= c;
            }
            uint32_t ex2 = tw & ~on & ~fo;
            uint32_t Q[9], K[9];
            #pragma unroll
            for (int d = 0; d < 9; ++d) { Q[d] = bd[u][d] & ex2; K[d] = 0u; }
            #pragma unroll
            for (int d1 = 0; d1 < 9; ++d1)
                #pragma unroll
                for (int d2 = d1 + 1; d2 < 9; ++d2) {
                    uint32_t P = Q[d1] & Q[d2];
                    #pragma unroll
                    for (int k = 0; k < 3; ++k) {
                        uint32_t m = P & (0x1C0E07u << (3 * k));
                        uint32_t s = (m & (m - 1u)) ? m : 0u;
                        K[d1] |= s; K[d2] |= s;
                    }
                }
            #pragma unroll
            for (int d = 0; d < 9; ++d)
                #pragma unroll
                for (int k = 0; k < 3; ++k) {
                    uint32_t bm = 0x1C0E07u << (3 * k);
                    uint32_t t = K[d] & bm;
                    uint32_t mask = t ? (~bm | t) : 0xFFFFFFFFu;
                    bd[u][d] &= mask;
                }
        }
    } // passes

    // ---------------- solved flag (AND across triple via shuffle) ----------------
    #pragma unroll
    for (int u = 0; u < 2; ++u) {
        uint32_t on = 0, tw = 0, fo = 0;
        #pragma unroll
        for (int d = 0; d < 9; ++d) {
            uint32_t c = on & bd[u][d];
            on ^= bd[u][d]; fo |= tw & c; tw ^= c;
        }
        uint32_t okb = ((on & ~tw & ~fo) == FULL27) ? 1u : 0u;
        uint32_t all = okb & (uint32_t)__shfl((int)okb, sl1, 64)
                           & (uint32_t)__shfl((int)okb, sl2, 64);
        if (valid && band == 0) solved[p0 + u * 16 + trip] = all ? 1.0f : 0.0f;
    }

    // ---------------- EXPAND (validated r8, rebased): pool -> float4 stores ----------
    // Bit B of pool == float p0*729 + B. Zero -> barrier -> atomicOr -> barrier.
    for (int j = lane; j < 744; j += 64) pool[j] = 0u;
    __syncthreads();
    if (valid) {
        #pragma unroll
        for (int u = 0; u < 2; ++u) {
            const int pbit = (u * 16 + trip) * 729;
            #pragma unroll
            for (int d = 0; d < 9; ++d) {
                int bitbase = pbit + d * 81 + band * 27;
                int di = bitbase >> 5;
                int sh = bitbase & 31;
                uint64_t both = (uint64_t)bd[u][d] << sh;
                atomicOr(&pool[di], (uint32_t)both);
                atomicOr(&pool[di + 1], (uint32_t)(both >> 32));
            }
        }
    }
    __syncthreads();
    {
        const int limit4 = PPW * 729 / 4;                    // 5832, exact (no tail)
        float4* dst4 = (float4*)(out + (size_t)p0 * 729);    // 23328 ≡ 0 mod 4: aligned
        #pragma unroll 4
        for (int i = 0; i < 92; ++i) {
            int j = i * 64 + lane;
            if (j < limit4) {
                uint32_t nib = (pool[j >> 3] >> ((j & 7) * 4)) & 0xFu;
                dst4[j] = make_float4((float)(nib & 1u), (float)((nib >> 1) & 1u),
                                      (float)((nib >> 2) & 1u), (float)((nib >> 3) & 1u));
            }
        }
    }
}

extern "C" void kernel_launch(void* const* d_in, const int* in_sizes, int n_in,
                              void* d_out, int out_size, void* d_ws, size_t ws_size,
                              hipStream_t stream) {
    const uint32_t* in = (const uint32_t*)d_in[0];   // float32 bits; nonzero <=> 1.0f
    float* out = (float*)d_out;
    float* solved = out + (size_t)NB * 729;
    // 1024 one-wave blocks, 32 puzzles each (ILP=2 per lane-triple)
    sudoku_kernel<<<NBLK, 64, 0, stream>>>(in, out, solved);
}

// Round 16
// 216.530 us; speedup vs baseline: 1.1124x; 1.1124x over previous
//
#include <hip/hip_runtime.h>
#include <stdint.h>

#define NB 32768
#define NPASS 4
#define FULL27 0x07FFFFFFu
#define NBF (NB * 729)     // total floats = 23,887,872
#define PPW 20             // puzzles per wave-block (20*729 = 14580 ≡ 0 mod 4 -> aligned float4)
#define NBLK ((NB + PPW - 1) / PPW)   // 1639 blocks

// Per-band bitboard: digit d, band b (rows 3b..3b+2), bit (r*9+c).
// BOX k mask within band: 0x1C0E07 << 3k ; COL c: 0x40201 << c ; ROW r: 0x1FF << 9r
// Flat float layout: puzzle p, digit d, band b, cell j  ==  p*729 + d*81 + b*27 + j.
//
// SESSION LEDGER (r15 = r13 reproduction, best config):
//   pack ~37us  (ceiling: 5 strategies tried — MLP batch, 16B loads, no-funnel,
//                pipelined, fine blocks — all 37-69us; scalar-bit-test packing
//                of 95.6MB runs ~2.5TB/s effective on gfx950)
//   solve ~50us (ceiling: occupancy 5.5->15%, barriers->shuffles, ILP=2 all
//                neutral-or-worse; 36 shuffle ops x 4 passes latency floor)
//   expand ~12us (at 93.5MB write roofline)
//   + ~110us harness-fixed cost (d_in restore + d_out/d_ws poison), confirmed
//     by total-kernel deltas of r6/r9/r11 and r5->r6 invariance.

__device__ __forceinline__ uint32_t colfold(uint32_t w) {
    return (w | (w >> 9) | (w >> 18)) & 0x1FFu;
}
__device__ __forceinline__ uint32_t colmaj2(uint32_t w) {   // columns with >=2 bits in band
    return ((w & (w >> 9)) | ((w | (w >> 9)) & (w >> 18))) & 0x1FFu;
}

__global__ __launch_bounds__(64)
void sudoku_kernel(const uint32_t* __restrict__ in, float* __restrict__ out,
                   float* __restrict__ solved) {
    __shared__ uint32_t pool[460];          // 14580 bits = 456 dw (+pad)
    const int lane = threadIdx.x;
    const int trip = lane / 3;              // 0..21 (20,21 = idle lanes 60..63)
    const int band = lane - trip * 3;
    const int bo1 = band == 2 ? 0 : band + 1;
    const int bo2 = band == 0 ? 2 : band - 1;
    int sl1 = trip * 3 + bo1; if (sl1 > 63) sl1 = 63;   // partner lanes
    int sl2 = trip * 3 + bo2; if (sl2 > 63) sl2 = 63;
    const int p0 = blockIdx.x * PPW;        // first puzzle of block
    const int p = p0 + trip;
    const bool valid = (trip < PPW) && (p < NB);

    // ---------------- PACK: coalesced loads -> ballot -> wave-private pool ----------
    // Pool bit j == input float p0*729 + j (j in [0, 14580)). 228 rounds of 64.
    {
        const int base = p0 * 729;                      // < 24M, fits int
        #pragma unroll 1
        for (int c = 0; c < 14; ++c) {                  // 14 chunks x 16 rounds
            uint32_t v[16];
            #pragma unroll
            for (int j = 0; j < 16; ++j) {
                int gi = base + (c * 16 + j) * 64 + lane;
                if (gi >= NBF) gi = NBF - 1;            // tail clamp (bits unused)
                v[j] = in[gi];
            }
            #pragma unroll
            for (int j = 0; j < 16; ++j) {
                unsigned long long m = __ballot(v[j] != 0u);
                if (lane == 0) {
                    int r = c * 16 + j;
                    pool[2 * r]     = (uint32_t)m;
                    pool[2 * r + 1] = (uint32_t)(m >> 32);
                }
            }
        }
        {   // rounds 224..227
            uint32_t v[4];
            #pragma unroll
            for (int j = 0; j < 4; ++j) {
                int gi = base + (224 + j) * 64 + lane;
                if (gi >= NBF) gi = NBF - 1;
                v[j] = in[gi];
            }
            #pragma unroll
            for (int j = 0; j < 4; ++j) {
                unsigned long long m = __ballot(v[j] != 0u);
                if (lane == 0) {
                    int r = 224 + j;
                    pool[2 * r]     = (uint32_t)m;
                    pool[2 * r + 1] = (uint32_t)(m >> 32);
                }
            }
        }
    }
    __syncthreads();

    // ---------------- EXTRACT: 9 band-words for this lane's puzzle ----------------
    uint32_t bd[9];
    {
        const int tx = trip >= PPW ? PPW - 1 : trip;    // keep idle lanes in-bounds
        const int bb0 = tx * 729 + band * 27;
        #pragma unroll
        for (int d = 0; d < 9; ++d) {
            int bb = bb0 + d * 81;
            int di = bb >> 5, sh = bb & 31;
            uint64_t both = (uint64_t)pool[di] | ((uint64_t)pool[di + 1] << 32);
            bd[d] = (uint32_t)(both >> sh) & FULL27;
        }
    }
    __syncthreads();    // extraction done before the pool is zeroed for expand

    // ---------------- SOLVE (validated r6/r8 logic, unchanged) ----------------
    #pragma unroll 1
    for (int pass = 0; pass < NPASS; ++pass) {
        // ---------- filter 'box' (band-local) ----------
        {
            uint32_t on = 0, tw = 0, fo = 0;
            #pragma unroll
            for (int d = 0; d < 9; ++d) {
                uint32_t c = on & bd[d];
                on ^= bd[d]; fo |= tw & c; tw ^= c;
            }
            uint32_t ex1 = on & ~tw & ~fo;
            #pragma unroll
            for (int d = 0; d < 9; ++d) {
                uint32_t s = bd[d] & ex1;
                #pragma unroll
                for (int k = 0; k < 3; ++k) {
                    uint32_t bm = 0x1C0E07u << (3 * k);
                    uint32_t sm = s & bm;
                    uint32_t multi = sm & (sm - 1u);
                    uint32_t keep = (sm == 0u) ? 0xFFFFFFFFu : (~bm | (multi ? 0u : sm));
                    bd[d] &= keep;
                }
            }
        }

        // ---------- pointing 'h' (band-local) ----------
        #pragma unroll
        for (int d = 0; d < 9; ++d) {
            uint32_t w = bd[d];
            uint32_t t = (w | (w >> 1) | (w >> 2)) & 0x01249249u;
            uint32_t sum = (t & 0x1FFu) + ((t >> 9) & 0x1FFu) + ((t >> 18) & 0x1FFu);
            uint32_t single = sum & ~(sum >> 1) & 0x49u;
            uint32_t point = t & (single * 0x40201u);
            uint32_t clearm = 0;
            #pragma unroll
            for (int r = 0; r < 3; ++r) {
                uint32_t pr = (point >> (9 * r)) & 0x1FFu;
                uint32_t multi = pr & (pr - 1u);
                uint32_t segkeep = multi ? 0u : pr * 7u;
                uint32_t rc = pr ? ((0x1FFu & ~segkeep) << (9 * r)) : 0u;
                clearm |= rc;
            }
            bd[d] = w & ~clearm;
        }

        // ---------- pointing 'v' (cross-band via shuffle) ----------
        {
            uint32_t pnt[9];
            #pragma unroll
            for (int d = 0; d < 9; ++d) {
                uint32_t w = bd[d];
                uint32_t q = colfold(w);
                uint32_t u = (q & 0x49u) + ((q >> 1) & 0x49u) + ((q >> 2) & 0x49u);
                uint32_t single = u & ~(u >> 1) & 0x49u;
                pnt[d] = q & (single * 7u);
            }
            #pragma unroll
            for (int d = 0; d < 9; ++d) {
                uint32_t o = (uint32_t)__shfl((int)pnt[d], sl1, 64) |
                             (uint32_t)__shfl((int)pnt[d], sl2, 64);
                bd[d] &= ~(o * 0x40201u);
            }
        }

        // ---------- unique 'h' (band-local) ----------
        {
            uint32_t hid[9], has = 0;
            #pragma unroll
            for (int d = 0; d < 9; ++d) {
                uint32_t w = bd[d], h = 0;
                #pragma unroll
                for (int r = 0; r < 3; ++r) {
                    uint32_t x = w & (0x1FFu << (9 * r));
                    h |= (x & (x - 1u)) ? 0u : x;
                }
                hid[d] = h; has |= h;
            }
            #pragma unroll
            for (int d = 0; d < 9; ++d) bd[d] = (bd[d] & ~has) | hid[d];
        }

        // ---------- unique 'v' (cross-band via shuffle) ----------
        {
            uint32_t hid[9], has = 0;
            #pragma unroll
            for (int d = 0; d < 9; ++d) {
                uint32_t w = bd[d];
                uint32_t q0 = colfold(w), m0 = colmaj2(w);
                uint32_t ex = q0 | (m0 << 9);
                uint32_t ea = (uint32_t)__shfl((int)ex, sl1, 64);
                uint32_t eb = (uint32_t)__shfl((int)ex, sl2, 64);
                uint32_t qa = ea & 0x1FFu, ma = ea >> 9;
                uint32_t qb = eb & 0x1FFu, mb = eb >> 9;
                uint32_t ge2 = m0 | ma | mb | (q0 & qa) | (q0 & qb) | (qa & qb);
                uint32_t ex1c = (q0 | qa | qb) & ~ge2;   // column total count == 1
                hid[d] = w & ((ex1c & q0) * 0x40201u);
                has |= hid[d];
            }
            #pragma unroll
            for (int d = 0; d < 9; ++d) bd[d] = (bd[d] & ~has) | hid[d];
        }

        // ---------- unique 'box' (band-local) ----------
        {
            uint32_t hid[9], has = 0;
            #pragma unroll
            for (int d = 0; d < 9; ++d) {
                uint32_t w = bd[d], h = 0;
                #pragma unroll
                for (int k = 0; k < 3; ++k) {
                    uint32_t x = w & (0x1C0E07u << (3 * k));
                    h |= (x & (x - 1u)) ? 0u : x;
                }
                hid[d] = h; has |= h;
            }
            #pragma unroll
            for (int d = 0; d < 9; ++d) bd[d] = (bd[d] & ~has) | hid[d];
        }

        // ---------- doubles 'v' twice (cross-band via shuffle) ----------
        #pragma unroll 1
        for (int rep = 0; rep < 2; ++rep) {
            uint32_t on = 0, tw = 0, fo = 0;
            #pragma unroll
            for (int d = 0; d < 9; ++d) {
                uint32_t c = on & bd[d];
                on ^= bd[d]; fo |= tw & c; tw ^= c;
            }
            uint32_t ex2 = tw & ~on & ~fo;
            uint32_t Q[9], K[9];
            #pragma unroll
            for (int d = 0; d < 9; ++d) { Q[d] = bd[d] & ex2; K[d] = 0u; }
            #pragma unroll
            for (int d1 = 0; d1 < 9; ++d1)
                #pragma unroll
                for (int d2 = d1 + 1; d2 < 9; ++d2) {
                    uint32_t P = Q[d1] & Q[d2];
                    uint32_t f0 = colfold(P), g0 = colmaj2(P);
                    uint32_t ex = f0 | (g0 << 9);
                    uint32_t ea = (uint32_t)__shfl((int)ex, sl1, 64);
                    uint32_t eb = (uint32_t)__shfl((int)ex, sl2, 64);
                    uint32_t fa = ea & 0x1FFu, ga = ea >> 9;
                    uint32_t fb = eb & 0x1FFu, gb = eb >> 9;
                    // columns with >=2 exact-pair cells across the full column
                    uint32_t dup = g0 | ga | gb | (f0 & fa) | (f0 & fb) | (fa & fb);
                    uint32_t sK = P & (dup * 0x40201u);
                    K[d1] |= sK; K[d2] |= sK;
                }
            #pragma unroll
            for (int d = 0; d < 9; ++d) {
                uint32_t kc = colfold(K[d]);
                uint32_t cols = kc | (uint32_t)__shfl((int)kc, sl1, 64)
                                   | (uint32_t)__shfl((int)kc, sl2, 64);
                uint32_t em = cols * 0x40201u;
                bd[d] = (bd[d] & ~em) | K[d];
            }
        }

        // ---------- doubles 'box' (band-local) ----------
        {
            uint32_t on = 0, tw = 0, fo = 0;
            #pragma unroll
            for (int d = 0; d < 9; ++d) {
                uint32_t c = on & bd[d];
                on ^= bd[d]; fo |= tw & c; tw ^= c;
            }
            uint32_t ex2 = tw & ~on & ~fo;
            uint32_t Q[9], K[9];
            #pragma unroll
            for (int d = 0; d < 9; ++d) { Q[d] = bd[d] & ex2; K[d] = 0u; }
            #pragma unroll
            for (int d1 = 0; d1 < 9; ++d1)
                #pragma unroll
                for (int d2 = d1 + 1; d2 < 9; ++d2) {
                    uint32_t P = Q[d1] & Q[d2];
                    #pragma unroll
                    for (int k = 0; k < 3; ++k) {
                        uint32_t m = P & (0x1C0E07u << (3 * k));
                        uint32_t s = (m & (m - 1u)) ? m : 0u;
                        K[d1] |= s; K[d2] |= s;
                    }
                }
            #pragma unroll
            for (int d = 0; d < 9; ++d)
                #pragma unroll
                for (int k = 0; k < 3; ++k) {
                    uint32_t bm = 0x1C0E07u << (3 * k);
                    uint32_t t = K[d] & bm;
                    uint32_t mask = t ? (~bm | t) : 0xFFFFFFFFu;
                    bd[d] &= mask;
                }
        }
    } // passes

    // ---------------- solved flag (AND across triple via shuffle) ----------------
    {
        uint32_t on = 0, tw = 0, fo = 0;
        #pragma unroll
        for (int d = 0; d < 9; ++d) {
            uint32_t c = on & bd[d];
            on ^= bd[d]; fo |= tw & c; tw ^= c;
        }
        uint32_t okb = ((on & ~tw & ~fo) == FULL27) ? 1u : 0u;
        uint32_t all = okb & (uint32_t)__shfl((int)okb, sl1, 64)
                           & (uint32_t)__shfl((int)okb, sl2, 64);
        if (valid && band == 0) solved[p] = all ? 1.0f : 0.0f;
    }

    // ---------------- EXPAND (validated r8, rebased): pool -> float4 stores ----------
    // Bit B of pool == float p0*729 + B. Zero -> barrier -> atomicOr -> barrier.
    for (int j = lane; j < 456; j += 64) pool[j] = 0u;
    __syncthreads();
    if (valid) {
        const int pbit = trip * 729;
        #pragma unroll
        for (int d = 0; d < 9; ++d) {
            int bitbase = pbit + d * 81 + band * 27;
            int di = bitbase >> 5;
            int sh = bitbase & 31;
            uint64_t both = (uint64_t)bd[d] << sh;
            atomicOr(&pool[di], (uint32_t)both);
            atomicOr(&pool[di + 1], (uint32_t)(both >> 32));
        }
    }
    __syncthreads();
    {
        int nv = NB - p0; if (nv > PPW) nv = PPW;            // 20, or 8 in last block
        const int limit4 = nv * 729 / 4;                     // 3645 or 1458 (both exact)
        float4* dst4 = (float4*)(out + (size_t)p0 * 729);    // p0*729 ≡ 0 mod 4: aligned
        #pragma unroll 4
        for (int i = 0; i < 57; ++i) {
            int j = i * 64 + lane;
            if (j < limit4) {
                uint32_t nib = (pool[j >> 3] >> ((j & 7) * 4)) & 0xFu;
                dst4[j] = make_float4((float)(nib & 1u), (float)((nib >> 1) & 1u),
                                      (float)((nib >> 2) & 1u), (float)((nib >> 3) & 1u));
            }
        }
    }
}

extern "C" void kernel_launch(void* const* d_in, const int* in_sizes, int n_in,
                              void* d_out, int out_size, void* d_ws, size_t ws_size,
                              hipStream_t stream) {
    const uint32_t* in = (const uint32_t*)d_in[0];   // float32 bits; nonzero <=> 1.0f
    float* out = (float*)d_out;
    float* solved = out + (size_t)NB * 729;
    // 1639 one-wave blocks (20 puzzles each) -> dynamic CU backfill
    sudoku_kernel<<<NBLK, 64, 0, stream>>>(in, out, solved);
}